// Round 6
// baseline (452.745 us; speedup 1.0000x reference)
//
#include <hip/hip_runtime.h>

// GCN 2-layer on MI355X — Round 6: Round-5 pipeline + high-MLP agg kernels.
//
// g[j] = x[j]*dinv[j] (2 floats).  layer1: agg[i]=dinv[i]*(sum g[src]+g[i])@W1+b1
// h = relu(agg); hs2 = (h@W2)*dinv;  out[i] = dinv[i]*(sum hs2[src]+hs2[i])+b2
//
// Partition p = dst>>11 (2048 nodes, P=98). packed = (localdst<<18)|src (29b).
// agg kernels: 512 threads (all blocks resident, ~24 waves/CU) + manual 4x
// unroll (4 independent gathers in flight before each atomic group).
//
// ws (words): colTotal[1024] | colStart[1024] | cntmat[782*98 pad] | packed[E]
//  | dinv[n] | g[2n] | hs2[4n] | partial[6.42M]  (~57 MB)

#define EPB   8192   // edges per bucket block
#define PART  2048   // nodes per partition
#define LPBIT 11
#define SRCB  18     // src bits in packed
#define C1    16     // layer-1 chunks per partition
#define C2    8      // layer-2 chunks per partition

__global__ __launch_bounds__(512) void bucket_count_kernel(
    const int* __restrict__ dst, int* __restrict__ cntmat, int E, int P) {
    __shared__ int cnt[128];
    int tid = threadIdx.x;
    if (tid < 128) cnt[tid] = 0;
    __syncthreads();
    int base = blockIdx.x * EPB;
    #pragma unroll
    for (int k = 0; k < EPB; k += 512) {
        int e = base + k + tid;
        if (e < E) atomicAdd(&cnt[dst[e] >> LPBIT], 1);
    }
    __syncthreads();
    int* row = cntmat + (size_t)blockIdx.x * P;
    if (tid < P) row[tid] = cnt[tid];
}

// One block per partition column: exclusive scan over B block-counts.
__global__ __launch_bounds__(256) void col_scan_kernel(
    int* __restrict__ cntmat, int* __restrict__ colTotal, int B, int P) {
    __shared__ int sdata[256];
    int p = blockIdx.x, tid = threadIdx.x;
    int v[4];
    int s = 0;
    #pragma unroll
    for (int k = 0; k < 4; k++) {
        int b = tid * 4 + k;
        v[k] = (b < B) ? cntmat[(size_t)b * P + p] : 0;
        s += v[k];
    }
    int x = s;
    sdata[tid] = x;
    __syncthreads();
    for (int off = 1; off < 256; off <<= 1) {
        int t = (tid >= off) ? sdata[tid - off] : 0;
        __syncthreads();
        x += t;
        sdata[tid] = x;
        __syncthreads();
    }
    int run = x - s;
    #pragma unroll
    for (int k = 0; k < 4; k++) {
        int b = tid * 4 + k;
        if (b < B) cntmat[(size_t)b * P + p] = run;
        run += v[k];
    }
    if (tid == 255) colTotal[p] = x;
}

// Single block: exclusive scan colTotal[P] -> colStart[P+1].
__global__ __launch_bounds__(256) void total_scan_kernel(
    const int* __restrict__ colTotal, int* __restrict__ colStart,
    int P, int E) {
    __shared__ int sdata[256];
    int tid = threadIdx.x;
    int v[4];
    int s = 0;
    #pragma unroll
    for (int k = 0; k < 4; k++) {
        int i = tid * 4 + k;
        v[k] = (i < P) ? colTotal[i] : 0;
        s += v[k];
    }
    int x = s;
    sdata[tid] = x;
    __syncthreads();
    for (int off = 1; off < 256; off <<= 1) {
        int t = (tid >= off) ? sdata[tid - off] : 0;
        __syncthreads();
        x += t;
        sdata[tid] = x;
        __syncthreads();
    }
    int run = x - s;
    #pragma unroll
    for (int k = 0; k < 4; k++) {
        int i = tid * 4 + k;
        if (i < P) colStart[i] = run;
        run += v[k];
    }
    if (tid == 0) colStart[P] = E;
}

__global__ __launch_bounds__(512) void bucket_scatter_kernel(
    const int* __restrict__ src, const int* __restrict__ dst,
    const int* __restrict__ cntmat, const int* __restrict__ colStart,
    unsigned* __restrict__ packed, int E, int P) {
    __shared__ int cur[128];
    int tid = threadIdx.x;
    if (tid < P) cur[tid] = colStart[tid] + cntmat[(size_t)blockIdx.x * P + tid];
    __syncthreads();
    int base = blockIdx.x * EPB;
    #pragma unroll
    for (int k = 0; k < EPB; k += 512) {
        int e = base + k + tid;
        if (e < E) {
            int d = dst[e];
            int pos = atomicAdd(&cur[d >> LPBIT], 1);
            packed[pos] = ((unsigned)(d & (PART - 1)) << SRCB) | (unsigned)src[e];
        }
    }
}

// One block per partition: per-node degree hist -> dinv and g = x*dinv.
__global__ __launch_bounds__(512) void dinv_g_kernel(
    const unsigned* __restrict__ packed, const int* __restrict__ colStart,
    const float* __restrict__ x, float* __restrict__ dinv,
    float* __restrict__ g, int n) {
    __shared__ int hist[PART];
    int p = blockIdx.x, tid = threadIdx.x;
    for (int i = tid; i < PART; i += 512) hist[i] = 0;
    __syncthreads();
    int s0 = colStart[p], s1 = colStart[p + 1];
    for (int i = s0 + tid; i < s1; i += 512)
        atomicAdd(&hist[packed[i] >> SRCB], 1);
    __syncthreads();
    const float2* xp = (const float2*)x;
    float2* gp = (float2*)g;
    for (int j = tid; j < PART; j += 512) {
        int node = (p << LPBIT) + j;
        if (node < n) {
            float d = rsqrtf((float)hist[j] + 1.0f);  // +1 self-loop
            dinv[node] = d;
            float2 xv = xp[node];
            gp[node] = make_float2(xv.x * d, xv.y * d);
        }
    }
}

// Chunked layer-1 aggregation: block = (p, c); 2-float LDS accumulators.
// 512 threads, manual 4x unroll for memory-level parallelism.
__global__ __launch_bounds__(512) void agg1_kernel(
    const unsigned* __restrict__ packed, const int* __restrict__ colStart,
    const float* __restrict__ g, float* __restrict__ partial) {
    __shared__ float acc[2 * PART];
    int tid = threadIdx.x;
    int p = blockIdx.x >> 4, c = blockIdx.x & (C1 - 1);
    for (int i = tid; i < 2 * PART; i += 512) acc[i] = 0.0f;
    __syncthreads();
    int s0 = colStart[p], s1 = colStart[p + 1], len = s1 - s0;
    int cs = s0 + (len * c) / C1, ce = s0 + (len * (c + 1)) / C1;
    const float2* gp = (const float2*)g;
    int i = cs + tid;
    for (; i + 3 * 512 < ce; i += 4 * 512) {
        unsigned w0 = packed[i];
        unsigned w1 = packed[i + 512];
        unsigned w2 = packed[i + 1024];
        unsigned w3 = packed[i + 1536];
        float2 g0 = gp[w0 & ((1u << SRCB) - 1)];
        float2 g1 = gp[w1 & ((1u << SRCB) - 1)];
        float2 g2 = gp[w2 & ((1u << SRCB) - 1)];
        float2 g3 = gp[w3 & ((1u << SRCB) - 1)];
        int l0 = (int)(w0 >> SRCB), l1 = (int)(w1 >> SRCB);
        int l2 = (int)(w2 >> SRCB), l3 = (int)(w3 >> SRCB);
        atomicAdd(&acc[l0], g0.x); atomicAdd(&acc[PART + l0], g0.y);
        atomicAdd(&acc[l1], g1.x); atomicAdd(&acc[PART + l1], g1.y);
        atomicAdd(&acc[l2], g2.x); atomicAdd(&acc[PART + l2], g2.y);
        atomicAdd(&acc[l3], g3.x); atomicAdd(&acc[PART + l3], g3.y);
    }
    for (; i < ce; i += 512) {
        unsigned w = packed[i];
        float2 gv = gp[w & ((1u << SRCB) - 1)];
        int ld = (int)(w >> SRCB);
        atomicAdd(&acc[ld], gv.x);
        atomicAdd(&acc[PART + ld], gv.y);
    }
    __syncthreads();
    float2* pp = (float2*)partial + (size_t)blockIdx.x * PART;
    for (int j = tid; j < PART; j += 512)
        pp[j] = make_float2(acc[j], acc[PART + j]);
}

// Per-node reduce + fused dense epilogue: W1 + b1 + ReLU + W2 + dinv -> hs2.
__global__ __launch_bounds__(256) void reduce1_kernel(
    const float* __restrict__ partial, const float* __restrict__ g,
    const float* __restrict__ dinv, const float* __restrict__ W1,
    const float* __restrict__ b1, const float* __restrict__ W2,
    float* __restrict__ hs2, int n) {
    int i = blockIdx.x * 256 + threadIdx.x;
    if (i >= n) return;
    int p = i >> LPBIT, ld = i & (PART - 1);
    const float2* pp = (const float2*)partial;
    float s0 = 0.0f, s1 = 0.0f;
    #pragma unroll
    for (int c = 0; c < C1; c++) {
        float2 v = pp[(size_t)(p * C1 + c) * PART + ld];
        s0 += v.x;
        s1 += v.y;
    }
    float2 gv = ((const float2*)g)[i];
    float d = dinv[i];
    s0 = (s0 + gv.x) * d;
    s1 = (s1 + gv.y) * d;
    float h[8];
    #pragma unroll
    for (int f = 0; f < 8; f++)
        h[f] = fmaxf(s0 * W1[f] + s1 * W1[8 + f] + b1[f], 0.0f);
    float oc[4];
    #pragma unroll
    for (int k = 0; k < 4; k++) {
        float a = 0.0f;
        #pragma unroll
        for (int f = 0; f < 8; f++) a += h[f] * W2[4 * f + k];
        oc[k] = a * d;
    }
    float4 o;
    o.x = oc[0]; o.y = oc[1]; o.z = oc[2]; o.w = oc[3];
    *(float4*)(hs2 + 4 * (size_t)i) = o;
}

// Chunked layer-2 aggregation: 4-float LDS accumulators, 512 threads, 4x unroll.
__global__ __launch_bounds__(512) void agg2_kernel(
    const unsigned* __restrict__ packed, const int* __restrict__ colStart,
    const float* __restrict__ hs2, float* __restrict__ partial) {
    __shared__ float acc[4 * PART];
    int tid = threadIdx.x;
    int p = blockIdx.x >> 3, c = blockIdx.x & (C2 - 1);
    for (int i = tid; i < 4 * PART; i += 512) acc[i] = 0.0f;
    __syncthreads();
    int s0 = colStart[p], s1 = colStart[p + 1], len = s1 - s0;
    int cs = s0 + (len * c) / C2, ce = s0 + (len * (c + 1)) / C2;
    const float4* hp = (const float4*)hs2;
    int i = cs + tid;
    for (; i + 3 * 512 < ce; i += 4 * 512) {
        unsigned w0 = packed[i];
        unsigned w1 = packed[i + 512];
        unsigned w2 = packed[i + 1024];
        unsigned w3 = packed[i + 1536];
        float4 v0 = hp[w0 & ((1u << SRCB) - 1)];
        float4 v1 = hp[w1 & ((1u << SRCB) - 1)];
        float4 v2 = hp[w2 & ((1u << SRCB) - 1)];
        float4 v3 = hp[w3 & ((1u << SRCB) - 1)];
        int l0 = (int)(w0 >> SRCB), l1 = (int)(w1 >> SRCB);
        int l2 = (int)(w2 >> SRCB), l3 = (int)(w3 >> SRCB);
        atomicAdd(&acc[l0], v0.x); atomicAdd(&acc[PART + l0], v0.y);
        atomicAdd(&acc[2 * PART + l0], v0.z); atomicAdd(&acc[3 * PART + l0], v0.w);
        atomicAdd(&acc[l1], v1.x); atomicAdd(&acc[PART + l1], v1.y);
        atomicAdd(&acc[2 * PART + l1], v1.z); atomicAdd(&acc[3 * PART + l1], v1.w);
        atomicAdd(&acc[l2], v2.x); atomicAdd(&acc[PART + l2], v2.y);
        atomicAdd(&acc[2 * PART + l2], v2.z); atomicAdd(&acc[3 * PART + l2], v2.w);
        atomicAdd(&acc[l3], v3.x); atomicAdd(&acc[PART + l3], v3.y);
        atomicAdd(&acc[2 * PART + l3], v3.z); atomicAdd(&acc[3 * PART + l3], v3.w);
    }
    for (; i < ce; i += 512) {
        unsigned w = packed[i];
        float4 v = hp[w & ((1u << SRCB) - 1)];
        int ld = (int)(w >> SRCB);
        atomicAdd(&acc[ld], v.x);
        atomicAdd(&acc[PART + ld], v.y);
        atomicAdd(&acc[2 * PART + ld], v.z);
        atomicAdd(&acc[3 * PART + ld], v.w);
    }
    __syncthreads();
    float4* pp = (float4*)partial + (size_t)blockIdx.x * PART;
    for (int j = tid; j < PART; j += 512) {
        float4 v;
        v.x = acc[j];
        v.y = acc[PART + j];
        v.z = acc[2 * PART + j];
        v.w = acc[3 * PART + j];
        pp[j] = v;
    }
}

__global__ __launch_bounds__(256) void reduce2_kernel(
    const float* __restrict__ partial, const float* __restrict__ hs2,
    const float* __restrict__ dinv, const float* __restrict__ b2,
    float* __restrict__ out, int n) {
    int i = blockIdx.x * 256 + threadIdx.x;
    if (i >= n) return;
    int p = i >> LPBIT, ld = i & (PART - 1);
    const float4* pp = (const float4*)partial;
    float4 s = make_float4(0.f, 0.f, 0.f, 0.f);
    #pragma unroll
    for (int c = 0; c < C2; c++) {
        float4 v = pp[(size_t)(p * C2 + c) * PART + ld];
        s.x += v.x; s.y += v.y; s.z += v.z; s.w += v.w;
    }
    float4 h = *(const float4*)(hs2 + 4 * (size_t)i);
    float d = dinv[i];
    float4 o;
    o.x = d * (s.x + h.x) + b2[0];
    o.y = d * (s.y + h.y) + b2[1];
    o.z = d * (s.z + h.z) + b2[2];
    o.w = d * (s.w + h.w) + b2[3];
    *(float4*)(out + 4 * (size_t)i) = o;
}

extern "C" void kernel_launch(void* const* d_in, const int* in_sizes, int n_in,
                              void* d_out, int out_size, void* d_ws, size_t ws_size,
                              hipStream_t stream) {
    const float* x   = (const float*)d_in[0];
    const int*   ei  = (const int*)d_in[1];
    const float* W1  = (const float*)d_in[2];
    const float* b1  = (const float*)d_in[3];
    const float* W2  = (const float*)d_in[4];
    const float* b2  = (const float*)d_in[5];
    float* out = (float*)d_out;

    const int n = in_sizes[0] / 2;  // x is [N,2]
    const int E = in_sizes[1] / 2;  // edge_index is [2,E]
    const int* src = ei;
    const int* dst = ei + E;

    const int P = (n + PART - 1) >> LPBIT;  // 98
    const int B = (E + EPB - 1) / EPB;      // 782

    int* ws = (int*)d_ws;
    int* colTotal = ws;                                    // 1024
    int* colStart = ws + 1024;                             // 1024 (P+1 used)
    int* cntmat   = ws + 2048;                             // B*P
    size_t cm = ((size_t)B * P + 3) & ~(size_t)3;
    unsigned* packed = (unsigned*)(cntmat + cm);           // E
    float* dinv = (float*)(packed + E);                    // n
    float* g    = dinv + n;                                // 2n  (8B aligned)
    float* hs2  = g + 2 * (size_t)n;                       // 4n  (16B aligned)
    float* partial = hs2 + 4 * (size_t)n;                  // 6.42M words

    bucket_count_kernel  <<<B, 512, 0, stream>>>(dst, cntmat, E, P);
    col_scan_kernel      <<<P, 256, 0, stream>>>(cntmat, colTotal, B, P);
    total_scan_kernel    <<<1, 256, 0, stream>>>(colTotal, colStart, P, E);
    bucket_scatter_kernel<<<B, 512, 0, stream>>>(src, dst, cntmat, colStart, packed, E, P);
    dinv_g_kernel        <<<P, 512, 0, stream>>>(packed, colStart, x, dinv, g, n);
    agg1_kernel          <<<P * C1, 512, 0, stream>>>(packed, colStart, g, partial);
    reduce1_kernel       <<<(n + 255) / 256, 256, 0, stream>>>(partial, g, dinv, W1, b1, W2, hs2, n);
    agg2_kernel          <<<P * C2, 512, 0, stream>>>(packed, colStart, hs2, partial);
    reduce2_kernel       <<<(n + 255) / 256, 256, 0, stream>>>(partial, hs2, dinv, b2, out, n);
}